// Round 6
// baseline (46.298 us; speedup 1.0000x reference)
//
#include <hip/hip_runtime.h>

// PhysicsLoss: fused base-MSE + boundary MSE + continuity + NS-residual losses.
// inputs  (256,1,128,128) f32, outputs (256,3,128,128) f32, targets (256,3,128,128) f32
// -> scalar f32.
//
// R5: LDS-staged tile. R3/R4 were latency-bound: VGPR_Count=52 proves the
// compiler sank the 23 global loads into the compute (4-6 serialized L2/L3
// stalls/wave). Now each block stages u,v rows r0-2..r0+9 + p rows r0-1..r0+8
// (34 rows, 17KB LDS) as one batched load burst (sched_barrier-pinned), then
// all stencil reads are ~60cyc ds_read_b128 -> latency trivially hidden.

#define HH 128
#define WW 128
#define NI 126   // interior size (1:H-1)
#define NBLK 4096

template <int I> __device__ __forceinline__ float gc(const float4& f) {
    if constexpr (I == 0) return f.x;
    else if constexpr (I == 1) return f.y;
    else if constexpr (I == 2) return f.z;
    else return f.w;
}

// x-neighborhood value at 12-wide index IDX (0..3 -> left f4, 4..7 -> mid, 8..11 -> right)
template <int IDX>
__device__ __forceinline__ float xsel(const float4& l, const float4& m, const float4& r) {
    if constexpr (IDX < 4) return gc<IDX>(l);
    else if constexpr (IDX < 8) return gc<IDX - 4>(m);
    else return gc<IDX - 8>(r);
}

// torch.gradient 1st derivative from named neighbor scalars
__device__ __forceinline__ float grad1s(float m1, float a0, float p1, int i,
                                        float inv_h, float inv_2h) {
    if (i == 0) return (p1 - a0) * inv_h;
    if (i == NI - 1) return (a0 - m1) * inv_h;
    return (p1 - m1) * inv_2h;
}

// torch.gradient 2nd derivative (grad of grad), from named neighbor scalars
__device__ __forceinline__ float grad2s(float m2, float m1, float a0, float p1, float p2,
                                        int i, float inv_h, float inv_2h) {
    if (i == 0) {
        const float d1 = (p2 - a0) * inv_2h, d0 = (p1 - a0) * inv_h;
        return (d1 - d0) * inv_h;
    }
    if (i == 1) {
        const float d1 = (p2 - a0) * inv_2h, dm1 = (a0 - m1) * inv_h;
        return (d1 - dm1) * inv_2h;
    }
    if (i == NI - 1) {
        const float d0 = (a0 - m1) * inv_h, dm1 = (a0 - m2) * inv_2h;
        return (d0 - dm1) * inv_h;
    }
    if (i == NI - 2) {
        const float d1 = (p1 - a0) * inv_h, dm1 = (a0 - m2) * inv_2h;
        return (d1 - dm1) * inv_2h;
    }
    return (p2 - 2.f * a0 + m2) * inv_2h * inv_2h;
}

struct Acc { float base, bc, cont, ns; };

template <int Q>
__device__ __forceinline__ void do_pixel(
    int r, int c0, bool midrow,
    const float4& uxl, const float4& uxm, const float4& uxr,
    const float4& uym2, const float4& uym1, const float4& uyp1, const float4& uyp2,
    const float4& vxl, const float4& vxm, const float4& vxr,
    const float4& vym2, const float4& vym1, const float4& vyp1, const float4& vyp2,
    const float4& pxl, const float4& pxm, const float4& pxr,
    const float4& pym1, const float4& pyp1,
    const float4& t0, const float4& t1, const float4& t2, const float4& av,
    Acc& acc) {
    const int c = c0 + Q;
    const float u0 = xsel<Q + 4>(uxl, uxm, uxr);
    const float v0 = xsel<Q + 4>(vxl, vxm, vxr);
    const float p0 = xsel<Q + 4>(pxl, pxm, pxr);

    {
        const float d0 = p0 - gc<Q>(t0);
        const float d1 = u0 - gc<Q>(t1);
        const float d2 = v0 - gc<Q>(t2);
        acc.base += d0 * d0 + d1 * d1 + d2 * d2;
    }
    // boundary pieces (corner multiplicity matches the reference concat)
    if (c == 0 && midrow) { const float d = u0 - 0.01f; acc.bc += d * d; }
    if (c == WW - 1 && midrow) { acc.bc += p0 * p0; }
    if (r == 0 || r == HH - 1) { acc.bc += u0 * u0 + v0 * v0; }
    if ((c == 0 || c == WW - 1) && !midrow) { acc.bc += u0 * u0 + v0 * v0; }

    if (r >= 1 && r <= HH - 2 && c >= 1 && c <= WW - 2) {
        const int ic = c - 1, ir = r - 1;
        const float inv_sx = 127.0f / 1.2f, inv_2sx = 127.0f / 2.4f;
        const float inv_sy = 127.0f / 0.8f, inv_2sy = 127.0f / 1.6f;

        const float uxm2 = xsel<Q + 2>(uxl, uxm, uxr), uxm1 = xsel<Q + 3>(uxl, uxm, uxr);
        const float uxp1 = xsel<Q + 5>(uxl, uxm, uxr), uxp2 = xsel<Q + 6>(uxl, uxm, uxr);
        const float vxm2 = xsel<Q + 2>(vxl, vxm, vxr), vxm1 = xsel<Q + 3>(vxl, vxm, vxr);
        const float vxp1 = xsel<Q + 5>(vxl, vxm, vxr), vxp2 = xsel<Q + 6>(vxl, vxm, vxr);
        const float pxm1 = xsel<Q + 3>(pxl, pxm, pxr), pxp1 = xsel<Q + 5>(pxl, pxm, pxr);
        const float uym2s = gc<Q>(uym2), uym1s = gc<Q>(uym1);
        const float uyp1s = gc<Q>(uyp1), uyp2s = gc<Q>(uyp2);
        const float vym2s = gc<Q>(vym2), vym1s = gc<Q>(vym1);
        const float vyp1s = gc<Q>(vyp1), vyp2s = gc<Q>(vyp2);
        const float pym1s = gc<Q>(pym1), pyp1s = gc<Q>(pyp1);

        const float du_dx = grad1s(uxm1, u0, uxp1, ic, inv_sx, inv_2sx);
        const float du_dy = grad1s(uym1s, u0, uyp1s, ir, inv_sy, inv_2sy);
        const float dv_dx = grad1s(vxm1, v0, vxp1, ic, inv_sx, inv_2sx);
        const float dv_dy = grad1s(vym1s, v0, vyp1s, ir, inv_sy, inv_2sy);
        const float dp_dx = grad1s(pxm1, p0, pxp1, ic, inv_sx, inv_2sx);
        const float dp_dy = grad1s(pym1s, p0, pyp1s, ir, inv_sy, inv_2sy);
        const float du_dxx = grad2s(uxm2, uxm1, u0, uxp1, uxp2, ic, inv_sx, inv_2sx);
        const float du_dyy = grad2s(uym2s, uym1s, u0, uyp1s, uyp2s, ir, inv_sy, inv_2sy);
        const float dv_dxx = grad2s(vxm2, vxm1, v0, vxp1, vxp2, ic, inv_sx, inv_2sx);
        const float dv_dyy = grad2s(vym2s, vym1s, v0, vyp1s, vyp2s, ir, inv_sy, inv_2sy);

        const float alpha = gc<Q>(av);
        const float dvg = du_dx + dv_dy;
        acc.cont += dvg * dvg;
        // RHO = MU = 1
        const float xr_ = u0 * du_dx + v0 * du_dy + dp_dx - (du_dxx + du_dyy) + alpha * u0;
        const float yr_ = u0 * dv_dx + v0 * dv_dy + dp_dy - (dv_dxx + dv_dyy) + alpha * v0;
        acc.ns += xr_ * xr_ + yr_ * yr_;
    }
}

__global__ __launch_bounds__(256) void physics_loss_kernel(
    const float* __restrict__ inp, const float* __restrict__ out,
    const float* __restrict__ tgt, double* __restrict__ ws) {
    const int tid = threadIdx.x;
    const int grp = tid & 31;        // float4 group within row (32 per row)
    const int rloc = tid >> 5;       // 8 rows per block
    // XCD-chunked swizzle: XCD k (= blockIdx%8) owns work ids [k*512,(k+1)*512)
    const int bid = ((blockIdx.x & 7) << 9) | (blockIdx.x >> 3);
    const int b = bid >> 4;          // batch image
    const int r0 = (bid & 15) << 3;  // first row of the 8-row tile
    const int r = r0 | rloc;
    const int c0 = grp << 2;

    const float* O = out + (size_t)b * 3 * HH * WW;
    const float* T = tgt + (size_t)b * 3 * HH * WW;
    const float* A = inp + (size_t)b * HH * WW;
    const float* P = O;
    const float* U = O + HH * WW;
    const float* V = O + 2 * HH * WW;

    // ---- stage u rows r0-2..r0+9 (12), v rows r0-2..r0+9 (12), p rows r0-1..r0+8 (10)
    __shared__ float4 stile[34][32];   // 17408 B
    float4 vals[5];
    #pragma unroll
    for (int k = 0; k < 5; ++k) {
        if (k < 4 || tid < 64) {
            const int i = tid + k * 256;       // 0..1087
            const int row = i >> 5, g = i & 31;
            const float* base;
            int rr;
            if (row < 12)      { base = U; rr = r0 - 2 + row; }
            else if (row < 24) { base = V; rr = r0 - 2 + (row - 12); }
            else               { base = P; rr = r0 - 1 + (row - 24); }
            rr = rr < 0 ? 0 : (rr > 127 ? 127 : rr);
            vals[k] = *reinterpret_cast<const float4*>(base + rr * WW + g * 4);
        }
    }
    auto ld = [&](const float* base, int row, int gg) {
        return reinterpret_cast<const float4*>(base + row * WW)[gg];
    };
    const float4 t0 = ld(T, r, grp);
    const float4 t1 = ld(T + HH * WW, r, grp);
    const float4 t2 = ld(T + 2 * HH * WW, r, grp);
    const float4 av = ld(A, r, grp);
    __builtin_amdgcn_sched_barrier(0);   // pin the load burst above the writes
    #pragma unroll
    for (int k = 0; k < 5; ++k) {
        if (k < 4 || tid < 64) {
            const int i = tid + k * 256;
            reinterpret_cast<float4*>(stile)[i] = vals[k];
        }
    }
    __syncthreads();

    // ---- stencil reads from LDS (rows: su=0..11, sv=12..23, sp=24..33) ----
    const int gl = grp == 0 ? 0 : grp - 1;
    const int gr = grp == 31 ? 31 : grp + 1;
    const float4 uym2 = stile[rloc][grp],     uym1 = stile[rloc + 1][grp];
    const float4 uxl  = stile[rloc + 2][gl],  uxm  = stile[rloc + 2][grp];
    const float4 uxr  = stile[rloc + 2][gr];
    const float4 uyp1 = stile[rloc + 3][grp], uyp2 = stile[rloc + 4][grp];
    const float4 vym2 = stile[12 + rloc][grp],     vym1 = stile[12 + rloc + 1][grp];
    const float4 vxl  = stile[12 + rloc + 2][gl],  vxm  = stile[12 + rloc + 2][grp];
    const float4 vxr  = stile[12 + rloc + 2][gr];
    const float4 vyp1 = stile[12 + rloc + 3][grp], vyp2 = stile[12 + rloc + 4][grp];
    const float4 pym1 = stile[24 + rloc][grp];
    const float4 pxl  = stile[24 + rloc + 1][gl],  pxm  = stile[24 + rloc + 1][grp];
    const float4 pxr  = stile[24 + rloc + 1][gr];
    const float4 pyp1 = stile[24 + rloc + 2][grp];

    const bool midrow = (r >= 55 && r < 73);  // IN_BOT=55, IN_TOP=73
    Acc acc = {0.f, 0.f, 0.f, 0.f};

    do_pixel<0>(r, c0, midrow, uxl, uxm, uxr, uym2, uym1, uyp1, uyp2,
                vxl, vxm, vxr, vym2, vym1, vyp1, vyp2,
                pxl, pxm, pxr, pym1, pyp1, t0, t1, t2, av, acc);
    do_pixel<1>(r, c0, midrow, uxl, uxm, uxr, uym2, uym1, uyp1, uyp2,
                vxl, vxm, vxr, vym2, vym1, vyp1, vyp2,
                pxl, pxm, pxr, pym1, pyp1, t0, t1, t2, av, acc);
    do_pixel<2>(r, c0, midrow, uxl, uxm, uxr, uym2, uym1, uyp1, uyp2,
                vxl, vxm, vxr, vym2, vym1, vyp1, vyp2,
                pxl, pxm, pxr, pym1, pyp1, t0, t1, t2, av, acc);
    do_pixel<3>(r, c0, midrow, uxl, uxm, uxr, uym2, uym1, uyp1, uyp2,
                vxl, vxm, vxr, vym2, vym1, vyp1, vyp2,
                pxl, pxm, pxr, pym1, pyp1, t0, t1, t2, av, acc);

    // ---- block reduction: fp32 wave shuffle -> LDS -> f64 slot write ----
    float a_base = acc.base, a_bc = acc.bc, a_cont = acc.cont, a_ns = acc.ns;
    #pragma unroll
    for (int off = 32; off > 0; off >>= 1) {
        a_base += __shfl_down(a_base, off);
        a_bc   += __shfl_down(a_bc, off);
        a_cont += __shfl_down(a_cont, off);
        a_ns   += __shfl_down(a_ns, off);
    }
    __shared__ float red[4][4];
    const int wave = tid >> 6, lane = tid & 63;
    if (lane == 0) {
        red[wave][0] = a_base; red[wave][1] = a_bc;
        red[wave][2] = a_cont; red[wave][3] = a_ns;
    }
    __syncthreads();
    if (tid == 0) {
        double b0 = 0, b1 = 0, b2 = 0, b3 = 0;
        #pragma unroll
        for (int w = 0; w < 4; ++w) {
            b0 += red[w][0]; b1 += red[w][1]; b2 += red[w][2]; b3 += red[w][3];
        }
        double* slot = ws + (size_t)bid * 4;
        slot[0] = b0; slot[1] = b1; slot[2] = b2; slot[3] = b3;
    }
}

__global__ __launch_bounds__(256) void finalize_kernel(const double* __restrict__ ws,
                                                       float* __restrict__ out) {
    const int tid = threadIdx.x;
    double a0 = 0, a1 = 0, a2 = 0, a3 = 0;
    for (int b = tid; b < NBLK; b += 256) {
        const double* p = ws + (size_t)b * 4;
        a0 += p[0]; a1 += p[1]; a2 += p[2]; a3 += p[3];
    }
    #pragma unroll
    for (int off = 32; off > 0; off >>= 1) {
        a0 += __shfl_down(a0, off);
        a1 += __shfl_down(a1, off);
        a2 += __shfl_down(a2, off);
        a3 += __shfl_down(a3, off);
    }
    __shared__ double red[4][4];
    const int wave = tid >> 6, lane = tid & 63;
    if (lane == 0) {
        red[wave][0] = a0; red[wave][1] = a1; red[wave][2] = a2; red[wave][3] = a3;
    }
    __syncthreads();
    if (tid == 0) {
        double b0 = 0, b1 = 0, b2 = 0, b3 = 0;
        #pragma unroll
        for (int w = 0; w < 4; ++w) {
            b0 += red[w][0]; b1 += red[w][1]; b2 += red[w][2]; b3 += red[w][3];
        }
        const double loss_base = b0 / 300000.0;
        const double loss_cont = b2 / (256.0 * 126.0 * 126.0) / 1e-5;
        const double loss_ns   = b3 / (2.0 * 256.0 * 126.0 * 126.0) / 0.01;
        const double loss_bc   = b1 / (256.0 * 988.0);
        out[0] = (float)(0.10000000000000009 * loss_base +
                         0.3 * (loss_cont + loss_ns + loss_bc));
    }
}

extern "C" void kernel_launch(void* const* d_in, const int* in_sizes, int n_in,
                              void* d_out, int out_size, void* d_ws, size_t ws_size,
                              hipStream_t stream) {
    const float* inp = (const float*)d_in[0];
    const float* out = (const float*)d_in[1];
    const float* tgt = (const float*)d_in[2];
    float* o = (float*)d_out;
    double* ws = (double*)d_ws;

    hipLaunchKernelGGL(physics_loss_kernel, dim3(NBLK), dim3(256), 0, stream,
                       inp, out, tgt, ws);
    hipLaunchKernelGGL(finalize_kernel, dim3(1), dim3(256), 0, stream, ws, o);
}

// Round 7
// 31.563 us; speedup vs baseline: 1.4669x; 1.4669x over previous
//
#include <hip/hip_runtime.h>

// PhysicsLoss: fused base-MSE + boundary MSE + continuity + NS-residual losses.
// inputs  (256,1,128,128) f32, outputs (256,3,128,128) f32, targets (256,3,128,128) f32
// -> scalar f32.
//
// R6: R3 structure + raised register budget. R3/R4/R5 all compiled to VGPR=48-52:
// compiler targeted 8 waves/SIMD (64-VGPR cap), so 23 live float4s were either
// sunk into compute (serialized latency) or spilled (R5: 70MB scratch writes).
// __launch_bounds__(256,3) lifts the cap to ~170 VGPRs; sched_barrier(0) pins
// the 23-load burst above the compute -> one latency exposure, full MLP.

#define HH 128
#define WW 128
#define NI 126   // interior size (1:H-1)
#define NBLK 4096

template <int I> __device__ __forceinline__ float gc(const float4& f) {
    if constexpr (I == 0) return f.x;
    else if constexpr (I == 1) return f.y;
    else if constexpr (I == 2) return f.z;
    else return f.w;
}

// x-neighborhood value at 12-wide index IDX (0..3 -> left f4, 4..7 -> mid, 8..11 -> right)
template <int IDX>
__device__ __forceinline__ float xsel(const float4& l, const float4& m, const float4& r) {
    if constexpr (IDX < 4) return gc<IDX>(l);
    else if constexpr (IDX < 8) return gc<IDX - 4>(m);
    else return gc<IDX - 8>(r);
}

// torch.gradient 1st derivative from named neighbor scalars
__device__ __forceinline__ float grad1s(float m1, float a0, float p1, int i,
                                        float inv_h, float inv_2h) {
    if (i == 0) return (p1 - a0) * inv_h;
    if (i == NI - 1) return (a0 - m1) * inv_h;
    return (p1 - m1) * inv_2h;
}

// torch.gradient 2nd derivative (grad of grad), from named neighbor scalars
__device__ __forceinline__ float grad2s(float m2, float m1, float a0, float p1, float p2,
                                        int i, float inv_h, float inv_2h) {
    if (i == 0) {
        const float d1 = (p2 - a0) * inv_2h, d0 = (p1 - a0) * inv_h;
        return (d1 - d0) * inv_h;
    }
    if (i == 1) {
        const float d1 = (p2 - a0) * inv_2h, dm1 = (a0 - m1) * inv_h;
        return (d1 - dm1) * inv_2h;
    }
    if (i == NI - 1) {
        const float d0 = (a0 - m1) * inv_h, dm1 = (a0 - m2) * inv_2h;
        return (d0 - dm1) * inv_h;
    }
    if (i == NI - 2) {
        const float d1 = (p1 - a0) * inv_h, dm1 = (a0 - m2) * inv_2h;
        return (d1 - dm1) * inv_2h;
    }
    return (p2 - 2.f * a0 + m2) * inv_2h * inv_2h;
}

struct Acc { float base, bc, cont, ns; };

template <int Q>
__device__ __forceinline__ void do_pixel(
    int r, int c0, bool midrow,
    const float4& uxl, const float4& uxm, const float4& uxr,
    const float4& uym2, const float4& uym1, const float4& uyp1, const float4& uyp2,
    const float4& vxl, const float4& vxm, const float4& vxr,
    const float4& vym2, const float4& vym1, const float4& vyp1, const float4& vyp2,
    const float4& pxl, const float4& pxm, const float4& pxr,
    const float4& pym1, const float4& pyp1,
    const float4& t0, const float4& t1, const float4& t2, const float4& av,
    Acc& acc) {
    const int c = c0 + Q;
    const float u0 = xsel<Q + 4>(uxl, uxm, uxr);
    const float v0 = xsel<Q + 4>(vxl, vxm, vxr);
    const float p0 = xsel<Q + 4>(pxl, pxm, pxr);

    {
        const float d0 = p0 - gc<Q>(t0);
        const float d1 = u0 - gc<Q>(t1);
        const float d2 = v0 - gc<Q>(t2);
        acc.base += d0 * d0 + d1 * d1 + d2 * d2;
    }
    // boundary pieces (corner multiplicity matches the reference concat)
    if (c == 0 && midrow) { const float d = u0 - 0.01f; acc.bc += d * d; }
    if (c == WW - 1 && midrow) { acc.bc += p0 * p0; }
    if (r == 0 || r == HH - 1) { acc.bc += u0 * u0 + v0 * v0; }
    if ((c == 0 || c == WW - 1) && !midrow) { acc.bc += u0 * u0 + v0 * v0; }

    if (r >= 1 && r <= HH - 2 && c >= 1 && c <= WW - 2) {
        const int ic = c - 1, ir = r - 1;
        const float inv_sx = 127.0f / 1.2f, inv_2sx = 127.0f / 2.4f;
        const float inv_sy = 127.0f / 0.8f, inv_2sy = 127.0f / 1.6f;

        const float uxm2 = xsel<Q + 2>(uxl, uxm, uxr), uxm1 = xsel<Q + 3>(uxl, uxm, uxr);
        const float uxp1 = xsel<Q + 5>(uxl, uxm, uxr), uxp2 = xsel<Q + 6>(uxl, uxm, uxr);
        const float vxm2 = xsel<Q + 2>(vxl, vxm, vxr), vxm1 = xsel<Q + 3>(vxl, vxm, vxr);
        const float vxp1 = xsel<Q + 5>(vxl, vxm, vxr), vxp2 = xsel<Q + 6>(vxl, vxm, vxr);
        const float pxm1 = xsel<Q + 3>(pxl, pxm, pxr), pxp1 = xsel<Q + 5>(pxl, pxm, pxr);
        const float uym2s = gc<Q>(uym2), uym1s = gc<Q>(uym1);
        const float uyp1s = gc<Q>(uyp1), uyp2s = gc<Q>(uyp2);
        const float vym2s = gc<Q>(vym2), vym1s = gc<Q>(vym1);
        const float vyp1s = gc<Q>(vyp1), vyp2s = gc<Q>(vyp2);
        const float pym1s = gc<Q>(pym1), pyp1s = gc<Q>(pyp1);

        const float du_dx = grad1s(uxm1, u0, uxp1, ic, inv_sx, inv_2sx);
        const float du_dy = grad1s(uym1s, u0, uyp1s, ir, inv_sy, inv_2sy);
        const float dv_dx = grad1s(vxm1, v0, vxp1, ic, inv_sx, inv_2sx);
        const float dv_dy = grad1s(vym1s, v0, vyp1s, ir, inv_sy, inv_2sy);
        const float dp_dx = grad1s(pxm1, p0, pxp1, ic, inv_sx, inv_2sx);
        const float dp_dy = grad1s(pym1s, p0, pyp1s, ir, inv_sy, inv_2sy);
        const float du_dxx = grad2s(uxm2, uxm1, u0, uxp1, uxp2, ic, inv_sx, inv_2sx);
        const float du_dyy = grad2s(uym2s, uym1s, u0, uyp1s, uyp2s, ir, inv_sy, inv_2sy);
        const float dv_dxx = grad2s(vxm2, vxm1, v0, vxp1, vxp2, ic, inv_sx, inv_2sx);
        const float dv_dyy = grad2s(vym2s, vym1s, v0, vyp1s, vyp2s, ir, inv_sy, inv_2sy);

        const float alpha = gc<Q>(av);
        const float dvg = du_dx + dv_dy;
        acc.cont += dvg * dvg;
        // RHO = MU = 1
        const float xr_ = u0 * du_dx + v0 * du_dy + dp_dx - (du_dxx + du_dyy) + alpha * u0;
        const float yr_ = u0 * dv_dx + v0 * dv_dy + dp_dy - (dv_dxx + dv_dyy) + alpha * v0;
        acc.ns += xr_ * xr_ + yr_ * yr_;
    }
}

__global__ __launch_bounds__(256, 3) void physics_loss_kernel(
    const float* __restrict__ inp, const float* __restrict__ out,
    const float* __restrict__ tgt, double* __restrict__ ws) {
    const int tid = threadIdx.x;
    const int grp = tid & 31;        // float4 group within row (32 per row)
    const int rloc = tid >> 5;       // 8 rows per block
    // XCD-chunked swizzle: XCD k (= blockIdx%8) owns work ids [k*512,(k+1)*512)
    const int bid = ((blockIdx.x & 7) << 9) | (blockIdx.x >> 3);
    const int b = bid >> 4;          // batch image
    const int r = ((bid & 15) << 3) | rloc;
    const int c0 = grp << 2;

    const float* O = out + (size_t)b * 3 * HH * WW;
    const float* T = tgt + (size_t)b * 3 * HH * WW;
    const float* A = inp + (size_t)b * HH * WW;
    const float* P = O;
    const float* U = O + HH * WW;
    const float* V = O + 2 * HH * WW;

    const int gl = grp == 0 ? 0 : grp - 1;
    const int gr = grp == 31 ? 31 : grp + 1;
    const int rm2 = r < 2 ? 0 : r - 2;
    const int rm1 = r < 1 ? 0 : r - 1;
    const int rp1 = r > 126 ? 127 : r + 1;
    const int rp2 = r > 125 ? 127 : r + 2;

    auto ld = [&](const float* base, int row, int gg) {
        return reinterpret_cast<const float4*>(base + row * WW)[gg];
    };

    // 23 independent float4 loads — one pinned burst, all live in VGPRs
    const float4 uxl = ld(U, r, gl), uxm = ld(U, r, grp), uxr = ld(U, r, gr);
    const float4 uym2 = ld(U, rm2, grp), uym1 = ld(U, rm1, grp);
    const float4 uyp1 = ld(U, rp1, grp), uyp2 = ld(U, rp2, grp);
    const float4 vxl = ld(V, r, gl), vxm = ld(V, r, grp), vxr = ld(V, r, gr);
    const float4 vym2 = ld(V, rm2, grp), vym1 = ld(V, rm1, grp);
    const float4 vyp1 = ld(V, rp1, grp), vyp2 = ld(V, rp2, grp);
    const float4 pxl = ld(P, r, gl), pxm = ld(P, r, grp), pxr = ld(P, r, gr);
    const float4 pym1 = ld(P, rm1, grp), pyp1 = ld(P, rp1, grp);
    const float4 t0 = ld(T, r, grp);
    const float4 t1 = ld(T + HH * WW, r, grp);
    const float4 t2 = ld(T + 2 * HH * WW, r, grp);
    const float4 av = ld(A, r, grp);
    __builtin_amdgcn_sched_barrier(0);   // pin the load burst above the compute

    const bool midrow = (r >= 55 && r < 73);  // IN_BOT=55, IN_TOP=73
    Acc acc = {0.f, 0.f, 0.f, 0.f};

    do_pixel<0>(r, c0, midrow, uxl, uxm, uxr, uym2, uym1, uyp1, uyp2,
                vxl, vxm, vxr, vym2, vym1, vyp1, vyp2,
                pxl, pxm, pxr, pym1, pyp1, t0, t1, t2, av, acc);
    do_pixel<1>(r, c0, midrow, uxl, uxm, uxr, uym2, uym1, uyp1, uyp2,
                vxl, vxm, vxr, vym2, vym1, vyp1, vyp2,
                pxl, pxm, pxr, pym1, pyp1, t0, t1, t2, av, acc);
    do_pixel<2>(r, c0, midrow, uxl, uxm, uxr, uym2, uym1, uyp1, uyp2,
                vxl, vxm, vxr, vym2, vym1, vyp1, vyp2,
                pxl, pxm, pxr, pym1, pyp1, t0, t1, t2, av, acc);
    do_pixel<3>(r, c0, midrow, uxl, uxm, uxr, uym2, uym1, uyp1, uyp2,
                vxl, vxm, vxr, vym2, vym1, vyp1, vyp2,
                pxl, pxm, pxr, pym1, pyp1, t0, t1, t2, av, acc);

    // ---- block reduction: fp32 wave shuffle -> LDS -> f64 slot write ----
    float a_base = acc.base, a_bc = acc.bc, a_cont = acc.cont, a_ns = acc.ns;
    #pragma unroll
    for (int off = 32; off > 0; off >>= 1) {
        a_base += __shfl_down(a_base, off);
        a_bc   += __shfl_down(a_bc, off);
        a_cont += __shfl_down(a_cont, off);
        a_ns   += __shfl_down(a_ns, off);
    }
    __shared__ float red[4][4];
    const int wave = tid >> 6, lane = tid & 63;
    if (lane == 0) {
        red[wave][0] = a_base; red[wave][1] = a_bc;
        red[wave][2] = a_cont; red[wave][3] = a_ns;
    }
    __syncthreads();
    if (tid == 0) {
        double b0 = 0, b1 = 0, b2 = 0, b3 = 0;
        #pragma unroll
        for (int w = 0; w < 4; ++w) {
            b0 += red[w][0]; b1 += red[w][1]; b2 += red[w][2]; b3 += red[w][3];
        }
        double* slot = ws + (size_t)bid * 4;
        slot[0] = b0; slot[1] = b1; slot[2] = b2; slot[3] = b3;
    }
}

__global__ __launch_bounds__(256) void finalize_kernel(const double* __restrict__ ws,
                                                       float* __restrict__ out) {
    const int tid = threadIdx.x;
    double a0 = 0, a1 = 0, a2 = 0, a3 = 0;
    for (int b = tid; b < NBLK; b += 256) {
        const double* p = ws + (size_t)b * 4;
        a0 += p[0]; a1 += p[1]; a2 += p[2]; a3 += p[3];
    }
    #pragma unroll
    for (int off = 32; off > 0; off >>= 1) {
        a0 += __shfl_down(a0, off);
        a1 += __shfl_down(a1, off);
        a2 += __shfl_down(a2, off);
        a3 += __shfl_down(a3, off);
    }
    __shared__ double red[4][4];
    const int wave = tid >> 6, lane = tid & 63;
    if (lane == 0) {
        red[wave][0] = a0; red[wave][1] = a1; red[wave][2] = a2; red[wave][3] = a3;
    }
    __syncthreads();
    if (tid == 0) {
        double b0 = 0, b1 = 0, b2 = 0, b3 = 0;
        #pragma unroll
        for (int w = 0; w < 4; ++w) {
            b0 += red[w][0]; b1 += red[w][1]; b2 += red[w][2]; b3 += red[w][3];
        }
        const double loss_base = b0 / 300000.0;
        const double loss_cont = b2 / (256.0 * 126.0 * 126.0) / 1e-5;
        const double loss_ns   = b3 / (2.0 * 256.0 * 126.0 * 126.0) / 0.01;
        const double loss_bc   = b1 / (256.0 * 988.0);
        out[0] = (float)(0.10000000000000009 * loss_base +
                         0.3 * (loss_cont + loss_ns + loss_bc));
    }
}

extern "C" void kernel_launch(void* const* d_in, const int* in_sizes, int n_in,
                              void* d_out, int out_size, void* d_ws, size_t ws_size,
                              hipStream_t stream) {
    const float* inp = (const float*)d_in[0];
    const float* out = (const float*)d_in[1];
    const float* tgt = (const float*)d_in[2];
    float* o = (float*)d_out;
    double* ws = (double*)d_ws;

    hipLaunchKernelGGL(physics_loss_kernel, dim3(NBLK), dim3(256), 0, stream,
                       inp, out, tgt, ws);
    hipLaunchKernelGGL(finalize_kernel, dim3(1), dim3(256), 0, stream, ws, o);
}